// Round 1
// 115.676 us; speedup vs baseline: 1.0199x; 1.0199x over previous
//
#include <hip/hip_runtime.h>
#include <math.h>

#define TPB 256          // threads per block
#define SPT 2            // samples per thread
#define SPB (TPB * SPT)  // samples per block

// HW-approx rcp/sqrt (v_rcp_f32 / v_sqrt_f32, ~1e-6 rel err). Error budget:
// sigma3 needs only ~0.4% rel accuracy once det is exact (fp64), and the
// final sv^-2 terms tolerate 1e-6 rel against the absmax-scaled threshold.
__device__ __forceinline__ float fast_rcp(float x)  { return __builtin_amdgcn_rcpf(x); }
__device__ __forceinline__ float fast_sqrt(float x) { return __builtin_amdgcn_sqrtf(x); }

// Ortho term for one sample. fp32 throughout EXCEPT detW (fp64): det has
// catastrophic cancellation (true value ~sigma1*sigma2*sigma3 << term
// magnitudes) and sigma_min feeds (sigma+eps)^-2 ~ 1e12 which dominates the
// loss.
__device__ __forceinline__ void sample_ortho(const float4 t0, const float4 t1,
                                             const float4 t2, double& ortho)
{
    float w00 = t0.x, w01 = t0.y, w02 = t0.z;
    float w10 = t1.x, w11 = t1.y, w12 = t1.z;
    float w20 = t2.x, w21 = t2.y, w22 = t2.z;

    // A = W^T W (fp32)
    float A00 = w00*w00 + w10*w10 + w20*w20;
    float A11 = w01*w01 + w11*w11 + w21*w21;
    float A22 = w02*w02 + w12*w12 + w22*w22;
    float A01 = w00*w01 + w10*w11 + w20*w21;
    float A02 = w00*w02 + w10*w12 + w20*w22;
    float A12 = w01*w02 + w11*w12 + w21*w22;

    float I1 = A00 + A11 + A22;
    float I2 = (A00*A11 - A01*A01) + (A00*A22 - A02*A02) + (A11*A22 - A12*A12);

    // det(W) in fp64 — the one cancellation-critical quantity.
    double dw = (double)w00 * ((double)w11 * (double)w22 - (double)w12 * (double)w21)
              - (double)w01 * ((double)w10 * (double)w22 - (double)w12 * (double)w20)
              + (double)w02 * ((double)w10 * (double)w21 - (double)w11 * (double)w20);
    float I3 = (float)(dw * dw);   // det(A) >= 0

    // Smallest eigenvalue: monotone fixed point lam <- I3 / q(lam),
    // q(lam) = lam^2 - I1*lam + I2. Converges from below; immediate for the
    // near-singular samples that dominate the loss. HW rcp replaces the
    // ~10-instruction IEEE divide sequence.
    float lam = (I2 > 0.f) ? I3 * fast_rcp(I2) : 0.f;
    #pragma unroll
    for (int it = 0; it < 6; ++it) {
        float q = (lam - I1) * lam + I2;
        lam = (q > 0.f) ? I3 * fast_rcp(q) : lam;
    }
    if (lam < 0.f) lam = 0.f;

    // Remaining two eigenvalues from the deflated quadratic.
    float S = I1 - lam;
    float P = (lam - I1) * lam + I2;    // ~ lam1*lam2
    float disc = S * S - 4.f * P;
    disc = (disc > 0.f) ? fast_sqrt(disc) : 0.f;
    float l1 = 0.5f * (S + disc); if (l1 < 0.f) l1 = 0.f;
    float l2 = 0.5f * (S - disc); if (l2 < 0.f) l2 = 0.f;

    float s1 = fast_sqrt(l1)  + 1e-6f;
    float s2 = fast_sqrt(l2)  + 1e-6f;
    float s3 = fast_sqrt(lam) + 1e-6f;
    float q1 = s1 * s1, q2 = s2 * s2, q3 = s3 * s3;
    float inv = fast_rcp(q1 * q2 * q3);
    ortho += (double)((q1 + q2 + q3) + inv * (q2 * q3 + q1 * q3 + q1 * q2) - 6.f);
}

// Direct-load version: no LDS staging, no __syncthreads in the hot path.
// Every byte is consumed exactly once by exactly one thread, so there is no
// reuse for LDS to capture; the stride-48B per-lane float4 loads fully use
// every 64B line (adjacent lanes/loads cover the rest via L1). All 12
// dwordx4 loads per thread are issued before compute -> deep MLP per wave.
__global__ __launch_bounds__(256) void theta_loss_main(
    const float4* __restrict__ theta4,
    const float4* __restrict__ affine4,
    double* __restrict__ partial, int n)
{
    const int t = threadIdx.x;
    const int base = blockIdx.x * SPB + t;   // this thread's k-th sample: base + k*TPB
    double mse = 0.0, ortho = 0.0;

    float4 tv[SPT][3], av[SPT][3];
    #pragma unroll
    for (int k = 0; k < SPT; ++k) {
        int s = base + k * TPB;
        if (s < n) {
            int j = 3 * s;
            tv[k][0] = theta4[j];     tv[k][1] = theta4[j + 1];  tv[k][2] = theta4[j + 2];
            av[k][0] = affine4[j];    av[k][1] = affine4[j + 1]; av[k][2] = affine4[j + 2];
        } else {
            #pragma unroll
            for (int r = 0; r < 3; ++r) {
                tv[k][r] = make_float4(0.f, 0.f, 0.f, 0.f);
                av[k][r] = make_float4(0.f, 0.f, 0.f, 0.f);
            }
        }
    }

    // MSE: fp32 within a sample (<= 12 squared diffs, ~24 magnitude), widen once.
    #pragma unroll
    for (int k = 0; k < SPT; ++k) {
        float m = 0.f;
        #pragma unroll
        for (int r = 0; r < 3; ++r) {
            float dx = tv[k][r].x - av[k][r].x, dy = tv[k][r].y - av[k][r].y;
            float dz = tv[k][r].z - av[k][r].z, dw = tv[k][r].w - av[k][r].w;
            m += dx * dx + dy * dy + dz * dz + dw * dw;
        }
        mse += (double)m;
    }

    #pragma unroll
    for (int k = 0; k < SPT; ++k) {
        if (base + k * TPB < n)
            sample_ortho(tv[k][0], tv[k][1], tv[k][2], ortho);
    }

    // ---- block reduction: wave64 shuffle -> LDS -> per-block partial ----
    #pragma unroll
    for (int off = 32; off > 0; off >>= 1) {
        ortho += __shfl_down(ortho, off);
        mse   += __shfl_down(mse, off);
    }
    __shared__ double so[4], sm[4];
    int lane = t & 63, wv = t >> 6;
    if (lane == 0) { so[wv] = ortho; sm[wv] = mse; }
    __syncthreads();
    if (t == 0) {
        partial[2 * blockIdx.x]     = so[0] + so[1] + so[2] + so[3];
        partial[2 * blockIdx.x + 1] = sm[0] + sm[1] + sm[2] + sm[3];
    }
}

__global__ __launch_bounds__(256) void finalize_out(
    const double* __restrict__ partial, float* __restrict__ out,
    int nblocks, int n)
{
    double O = 0.0, M = 0.0;
    for (int i = threadIdx.x; i < nblocks; i += 256) {
        O += partial[2 * i];
        M += partial[2 * i + 1];
    }
    #pragma unroll
    for (int off = 32; off > 0; off >>= 1) {
        O += __shfl_down(O, off);
        M += __shfl_down(M, off);
    }
    __shared__ double so[4], sm[4];
    int lane = threadIdx.x & 63, wv = threadIdx.x >> 6;
    if (lane == 0) { so[wv] = O; sm[wv] = M; }
    __syncthreads();
    if (threadIdx.x == 0) {
        double Ot = so[0] + so[1] + so[2] + so[3];
        double Mt = sm[0] + sm[1] + sm[2] + sm[3];
        out[0] = (float)(Ot / (double)n);
        out[1] = (float)(Mt / (12.0 * (double)n));
    }
}

extern "C" void kernel_launch(void* const* d_in, const int* in_sizes, int n_in,
                              void* d_out, int out_size, void* d_ws, size_t ws_size,
                              hipStream_t stream) {
    const float4* theta4  = (const float4*)d_in[0];
    const float4* affine4 = (const float4*)d_in[1];
    double* partial = (double*)d_ws;
    float* out = (float*)d_out;
    int n = in_sizes[0] / 12;           // samples of 3x4

    int blocks = (n + SPB - 1) / SPB;   // 2048 for n = 1M
    theta_loss_main<<<blocks, TPB, 0, stream>>>(theta4, affine4, partial, n);
    finalize_out<<<1, 256, 0, stream>>>(partial, out, blocks, n);
}